// Round 1
// baseline (97.439 us; speedup 1.0000x reference)
//
#include <hip/hip_runtime.h>

// LearnableDemosaick: B=16,H=512,W=512,K=8,f=5, fp32.
// out = is_green ? mosaick : softmax_k(sel_conv) . green_conv
// is_green = (y%2)==(x%2). Edge-clamped 5x5 cross-correlation.

#define BDIM 256
#define TW 128          // tile width (pixels)
#define TH 8            // tile height (pixels)
#define LW (TW + 4)     // 132 LDS row stride (floats)
#define LH (TH + 4)     // 12 rows

__device__ __forceinline__ float softmax_mix(const float s[8], const float g[8]) {
    float m = s[0];
#pragma unroll
    for (int k = 1; k < 8; ++k) m = fmaxf(m, s[k]);
    float num = 0.f, den = 0.f;
#pragma unroll
    for (int k = 0; k < 8; ++k) {
        float e = __expf(s[k] - m);
        num = fmaf(e, g[k], num);
        den += e;
    }
    return num / den;
}

__global__ __launch_bounds__(BDIM) void demosaick_kernel(
    const float* __restrict__ mos,   // [B,1,H,W]
    const float* __restrict__ sf,    // [5,5,8]  (dy,dx,k)
    const float* __restrict__ gf,    // [5,5,8]
    float* __restrict__ out,         // [B,1,H,W]
    int H, int W)
{
    __shared__ float tile[LH * LW];

    const int b     = blockIdx.z;
    const int tileX = blockIdx.x * TW;
    const int tileY = blockIdx.y * TH;
    const float* img = mos + (size_t)b * H * W;

    // --- stage tile (with 2-halo, edge-clamped) into LDS ---
    for (int i = threadIdx.x; i < LH * LW; i += BDIM) {
        int r = i / LW;
        int c = i - r * LW;
        int gy = tileY - 2 + r; gy = min(max(gy, 0), H - 1);
        int gx = tileX - 2 + c; gx = min(max(gx, 0), W - 1);
        tile[i] = img[(size_t)gy * W + gx];
    }
    __syncthreads();

    const int tx = threadIdx.x & 63;   // 0..63  -> x quad
    const int ty = threadIdx.x >> 6;   // 0..3   -> y quad
    const int lx = 2 * tx + 2;         // local coord of (y0,x0) inside tile
    const int ly = 2 * ty + 2;

    // Quad (y0,x0): tileY,tileX even => (y0,x0) & (y0+1,x0+1) are green,
    // conv A at (y0, x0+1), conv B at (y0+1, x0).
    float sa[8], ga[8], sb[8], gb[8];
#pragma unroll
    for (int k = 0; k < 8; ++k) { sa[k] = ga[k] = sb[k] = gb[k] = 0.f; }

#pragma unroll
    for (int dy = 0; dy < 5; ++dy) {
#pragma unroll
        for (int dx = 0; dx < 5; ++dx) {
            const float va = tile[(ly + dy - 2) * LW + (lx + 1 + dx - 2)];
            const float vb = tile[(ly + 1 + dy - 2) * LW + (lx + dx - 2)];
            const float* fs = sf + (dy * 5 + dx) * 8;   // wave-uniform -> s_load
            const float* fg = gf + (dy * 5 + dx) * 8;
#pragma unroll
            for (int k = 0; k < 8; ++k) {
                const float fsv = fs[k];
                const float fgv = fg[k];
                sa[k] = fmaf(va, fsv, sa[k]);
                ga[k] = fmaf(va, fgv, ga[k]);
                sb[k] = fmaf(vb, fsv, sb[k]);
                gb[k] = fmaf(vb, fgv, gb[k]);
            }
        }
    }

    const float interpA = softmax_mix(sa, ga);
    const float interpB = softmax_mix(sb, gb);

    const float green0 = tile[ly * LW + lx];              // (y0, x0)
    const float green1 = tile[(ly + 1) * LW + lx + 1];    // (y0+1, x0+1)

    const int y0 = tileY + 2 * ty;
    const int x0 = tileX + 2 * tx;
    float* orow0 = out + (size_t)b * H * W + (size_t)y0 * W + x0;
    float* orow1 = orow0 + W;

    // coalesced float2 stores (x0 even -> 8B aligned)
    *reinterpret_cast<float2*>(orow0) = make_float2(green0, interpA);
    *reinterpret_cast<float2*>(orow1) = make_float2(interpB, green1);
}

extern "C" void kernel_launch(void* const* d_in, const int* in_sizes, int n_in,
                              void* d_out, int out_size, void* d_ws, size_t ws_size,
                              hipStream_t stream) {
    const float* mos = (const float*)d_in[0];
    const float* sf  = (const float*)d_in[1];
    const float* gf  = (const float*)d_in[2];
    float* out = (float*)d_out;

    const int H = 512, W = 512;
    const int B = in_sizes[0] / (H * W);   // 16

    dim3 grid(W / TW, H / TH, B);          // (4, 64, 16)
    dim3 block(BDIM);
    demosaick_kernel<<<grid, block, 0, stream>>>(mos, sf, gf, out, H, W);
}